// Round 7
// baseline (37.627 us; speedup 1.0000x reference)
//
#include <hip/hip_runtime.h>

#define H 4096
#define BLOCK 256
#define PER_THREAD (H / BLOCK)   // 16 floats/thread
#define VECS (PER_THREAD / 4)    // 4 float4 per thread

typedef float f32x4 __attribute__((ext_vector_type(4)));
typedef float f32x2 __attribute__((ext_vector_type(2)));

__global__ __launch_bounds__(BLOCK, 8) void quant_int4_kernel(
    const float* __restrict__ x,
    float* __restrict__ out_packed,   // packed int8 values, stored as float
    float* __restrict__ out_scales,   // per-row scales
    float r7)                         // fl32(1/7), host-computed
{
    const int row = blockIdx.x;
    const int t = threadIdx.x;
    const f32x4* xr = reinterpret_cast<const f32x4*>(x + (size_t)row * H);

    // ---- load row into registers (coalesced 16B, nt = no L2 alloc), absmax ----
    f32x4 v[VECS];
    float m = 0.0f;
#pragma unroll
    for (int j = 0; j < VECS; ++j) {
        v[j] = __builtin_nontemporal_load(&xr[t + BLOCK * j]);
        m = fmaxf(m, fmaxf(fmaxf(fabsf(v[j].x), fabsf(v[j].y)),
                           fmaxf(fabsf(v[j].z), fabsf(v[j].w))));
    }

    // ---- wave64 butterfly max-reduce (exact) ----
#pragma unroll
    for (int off = 32; off > 0; off >>= 1)
        m = fmaxf(m, __shfl_xor(m, off, 64));

    // ---- cross-wave reduce via LDS, broadcast row absmax ----
    __shared__ float smax[BLOCK / 64];
    const int wave = t >> 6;
    if ((t & 63) == 0) smax[wave] = m;
    __syncthreads();
    if (t == 0) {
        float mm = smax[0];
#pragma unroll
        for (int w = 1; w < BLOCK / 64; ++w) mm = fmaxf(mm, smax[w]);
        smax[0] = mm;
    }
    __syncthreads();
    const float absmax = smax[0];

    // ==== FROZEN NUMERICS (verified round 5, absmax 1.0) ====
    // XLA-style scale: s = fl32( fl32(absmax*0.9f) * fl32(1/7) ), then max(1e-8).
    // asm barrier stops fast-math from folding 0.9f*r7 into one constant.
    float tt = absmax * 0.9f;          // exact single f32 op
    asm volatile("" : "+v"(tt));
    float s = tt * r7;                 // exact single f32 op
    s = fmaxf(s, 1e-8f);

    // inv = 1/s in f64, Newton-refined; (f32)((f64)x*inv) == fl32(x/s) exactly
    // (quotient never an f32 midpoint; err 2^-51 << 2^-48 midpoint gap).
    double s64 = (double)s;
    asm volatile("" : "+v"(s64));
    double inv = 1.0 / s64;
    inv = inv * (2.0 - s64 * inv);     // NR -> ~0.5 ulp f64
    asm volatile("" : "+v"(inv));
    // ==== END FROZEN NUMERICS ====

    // ---- quantize RNE, clip, pack two int4/byte, nt-store coalesced 8B ----
    f32x2* outp = reinterpret_cast<f32x2*>(out_packed + (size_t)row * (H / 2));
#pragma unroll
    for (int j = 0; j < VECS; ++j) {
        float qf0 = (float)((double)v[j].x * inv);
        float qf1 = (float)((double)v[j].y * inv);
        float qf2 = (float)((double)v[j].z * inv);
        float qf3 = (float)((double)v[j].w * inv);
        int q0 = (int)rintf(qf0); q0 = max(-8, min(7, q0));
        int q1 = (int)rintf(qf1); q1 = max(-8, min(7, q1));
        int q2 = (int)rintf(qf2); q2 = max(-8, min(7, q2));
        int q3 = (int)rintf(qf3); q3 = max(-8, min(7, q3));
        int b0 = ((q1 & 0xF) << 4) | (q0 & 0xF);   // elem1 -> high nibble
        int b1 = ((q3 & 0xF) << 4) | (q2 & 0xF);
        f32x2 o;
        o.x = (float)(signed char)(b0 & 0xFF);      // value of the packed int8
        o.y = (float)(signed char)(b1 & 0xFF);
        __builtin_nontemporal_store(o, &outp[t + BLOCK * j]);
    }

    if (t == 0) __builtin_nontemporal_store(s, &out_scales[row]);
}

extern "C" void kernel_launch(void* const* d_in, const int* in_sizes, int n_in,
                              void* d_out, int out_size, void* d_ws, size_t ws_size,
                              hipStream_t stream) {
    const float* x = (const float*)d_in[0];
    const int n = in_sizes[0];          // 4*2048*4096
    const int rows = n / H;             // 8192
    float* out = (float*)d_out;
    float* out_packed = out;            // n/2 packed values (as float)
    float* out_scales = out + (size_t)n / 2;  // rows scales

    const float r7 = 1.0f / 7.0f;       // compile-time fold: fl32(1/7)
    quant_int4_kernel<<<rows, BLOCK, 0, stream>>>(x, out_packed, out_scales, r7);
}

// Round 8
// 33.908 us; speedup vs baseline: 1.1097x; 1.1097x over previous
//
#include <hip/hip_runtime.h>

#define H 4096
#define BLOCK 512
#define PER_THREAD (H / BLOCK)   // 8 floats/thread
// thread t loads float4 indices {2t, 2t+1} -> 8 contiguous floats,
// producing 4 packed bytes -> 4 output floats = one coalesced f32x4 store.

typedef float f32x4 __attribute__((ext_vector_type(4)));

__global__ __launch_bounds__(BLOCK) void quant_int4_kernel(
    const float* __restrict__ x,
    float* __restrict__ out_packed,   // packed int8 values, stored as float
    float* __restrict__ out_scales,   // per-row scales
    float r7)                         // fl32(1/7), host-computed
{
    const int row = blockIdx.x;
    const int t = threadIdx.x;
    const f32x4* xr = reinterpret_cast<const f32x4*>(x + (size_t)row * H);

    // ---- load 8 contiguous floats (2x16B, coalesced), per-thread absmax ----
    f32x4 va = xr[2 * t];
    f32x4 vb = xr[2 * t + 1];
    float m = fmaxf(fmaxf(fmaxf(fabsf(va.x), fabsf(va.y)),
                          fmaxf(fabsf(va.z), fabsf(va.w))),
                    fmaxf(fmaxf(fabsf(vb.x), fabsf(vb.y)),
                          fmaxf(fabsf(vb.z), fabsf(vb.w))));

    // ---- wave64 butterfly max-reduce (exact) ----
#pragma unroll
    for (int off = 32; off > 0; off >>= 1)
        m = fmaxf(m, __shfl_xor(m, off, 64));

    // ---- cross-wave reduce via LDS, broadcast row absmax ----
    __shared__ float smax[BLOCK / 64];
    const int wave = t >> 6;
    if ((t & 63) == 0) smax[wave] = m;
    __syncthreads();
    if (t == 0) {
        float mm = smax[0];
#pragma unroll
        for (int w = 1; w < BLOCK / 64; ++w) mm = fmaxf(mm, smax[w]);
        smax[0] = mm;
    }
    __syncthreads();
    const float absmax = smax[0];

    // ==== FROZEN NUMERICS (verified round 5, absmax 1.0) ====
    // XLA-style scale: s = fl32( fl32(absmax*0.9f) * fl32(1/7) ), then max(1e-8).
    // asm barrier stops fast-math from folding 0.9f*r7 into one constant.
    float tt = absmax * 0.9f;          // exact single f32 op
    asm volatile("" : "+v"(tt));
    float s = tt * r7;                 // exact single f32 op
    s = fmaxf(s, 1e-8f);

    // inv = 1/s in f64, Newton-refined; (f32)((f64)x*inv) == fl32(x/s) exactly
    // (quotient never an f32 midpoint; err 2^-51 << 2^-48 midpoint gap).
    double s64 = (double)s;
    asm volatile("" : "+v"(s64));
    double inv = 1.0 / s64;
    inv = inv * (2.0 - s64 * inv);     // NR -> ~0.5 ulp f64
    asm volatile("" : "+v"(inv));
    // ==== END FROZEN NUMERICS ====

    // ---- quantize RNE, clip, pack 8 values -> 4 bytes -> one f32x4 store ----
    f32x4* outp = reinterpret_cast<f32x4*>(out_packed + (size_t)row * (H / 2));
    float qa0 = (float)((double)va.x * inv);
    float qa1 = (float)((double)va.y * inv);
    float qa2 = (float)((double)va.z * inv);
    float qa3 = (float)((double)va.w * inv);
    float qb0 = (float)((double)vb.x * inv);
    float qb1 = (float)((double)vb.y * inv);
    float qb2 = (float)((double)vb.z * inv);
    float qb3 = (float)((double)vb.w * inv);
    int a0 = (int)rintf(qa0); a0 = max(-8, min(7, a0));
    int a1 = (int)rintf(qa1); a1 = max(-8, min(7, a1));
    int a2 = (int)rintf(qa2); a2 = max(-8, min(7, a2));
    int a3 = (int)rintf(qa3); a3 = max(-8, min(7, a3));
    int b0 = (int)rintf(qb0); b0 = max(-8, min(7, b0));
    int b1 = (int)rintf(qb1); b1 = max(-8, min(7, b1));
    int b2 = (int)rintf(qb2); b2 = max(-8, min(7, b2));
    int b3 = (int)rintf(qb3); b3 = max(-8, min(7, b3));
    f32x4 o;
    o.x = (float)(signed char)((((a1 & 0xF) << 4) | (a0 & 0xF)) & 0xFF);
    o.y = (float)(signed char)((((a3 & 0xF) << 4) | (a2 & 0xF)) & 0xFF);
    o.z = (float)(signed char)((((b1 & 0xF) << 4) | (b0 & 0xF)) & 0xFF);
    o.w = (float)(signed char)((((b3 & 0xF) << 4) | (b2 & 0xF)) & 0xFF);
    outp[t] = o;

    if (t == 0) out_scales[row] = s;
}

extern "C" void kernel_launch(void* const* d_in, const int* in_sizes, int n_in,
                              void* d_out, int out_size, void* d_ws, size_t ws_size,
                              hipStream_t stream) {
    const float* x = (const float*)d_in[0];
    const int n = in_sizes[0];          // 4*2048*4096
    const int rows = n / H;             // 8192
    float* out = (float*)d_out;
    float* out_packed = out;            // n/2 packed values (as float)
    float* out_scales = out + (size_t)n / 2;  // rows scales

    const float r7 = 1.0f / 7.0f;       // compile-time fold: fl32(1/7)
    quant_int4_kernel<<<rows, BLOCK, 0, stream>>>(x, out_packed, out_scales, r7);
}

// Round 9
// 33.715 us; speedup vs baseline: 1.1160x; 1.0057x over previous
//
#include <hip/hip_runtime.h>

#define H 4096
#define BLOCK 512
#define PER_THREAD (H / BLOCK)   // 8 floats/thread
// thread t loads float4 indices {2t, 2t+1} -> 8 contiguous floats,
// producing 4 packed bytes -> 4 output floats = one coalesced f32x4 store.

typedef float f32x4 __attribute__((ext_vector_type(4)));

__global__ __launch_bounds__(BLOCK) void quant_int4_kernel(
    const float* __restrict__ x,
    float* __restrict__ out_packed,   // packed int8 values, stored as float
    float* __restrict__ out_scales,   // per-row scales
    float r7)                         // fl32(1/7), host-computed
{
    const int row = blockIdx.x;
    const int t = threadIdx.x;
    const f32x4* xr = reinterpret_cast<const f32x4*>(x + (size_t)row * H);

    // ---- load 8 contiguous floats (2x16B, coalesced, CACHED), absmax ----
    f32x4 va = xr[2 * t];
    f32x4 vb = xr[2 * t + 1];
    float m = fmaxf(fmaxf(fmaxf(fabsf(va.x), fabsf(va.y)),
                          fmaxf(fabsf(va.z), fabsf(va.w))),
                    fmaxf(fmaxf(fabsf(vb.x), fabsf(vb.y)),
                          fmaxf(fabsf(vb.z), fabsf(vb.w))));

    // ---- wave64 butterfly max-reduce (exact) ----
#pragma unroll
    for (int off = 32; off > 0; off >>= 1)
        m = fmaxf(m, __shfl_xor(m, off, 64));

    // ---- cross-wave reduce via LDS, broadcast row absmax ----
    __shared__ float smax[BLOCK / 64];
    const int wave = t >> 6;
    if ((t & 63) == 0) smax[wave] = m;
    __syncthreads();
    if (t == 0) {
        float mm = smax[0];
#pragma unroll
        for (int w = 1; w < BLOCK / 64; ++w) mm = fmaxf(mm, smax[w]);
        smax[0] = mm;
    }
    __syncthreads();
    const float absmax = smax[0];

    // ==== FROZEN NUMERICS (verified round 5/8, absmax 1.0) ====
    // XLA-style scale: s = fl32( fl32(absmax*0.9f) * fl32(1/7) ), then max(1e-8).
    // asm barrier stops fast-math from folding 0.9f*r7 into one constant.
    float tt = absmax * 0.9f;          // exact single f32 op
    asm volatile("" : "+v"(tt));
    float s = tt * r7;                 // exact single f32 op
    s = fmaxf(s, 1e-8f);

    // inv = 1/s in f64, Newton-refined; (f32)((f64)x*inv) == fl32(x/s) exactly
    // (quotient never an f32 midpoint; err 2^-51 << 2^-48 midpoint gap).
    double s64 = (double)s;
    asm volatile("" : "+v"(s64));
    double inv = 1.0 / s64;
    inv = inv * (2.0 - s64 * inv);     // NR -> ~0.5 ulp f64
    asm volatile("" : "+v"(inv));
    // ==== END FROZEN NUMERICS ====

    // ---- quantize RNE, clip, pack 8 values -> 4 bytes -> one NT f32x4 store ----
    // Output is write-once, never re-read by us, and overwritten by the
    // harness between replays -> stream it past L2/L3 (no write-allocate).
    f32x4* outp = reinterpret_cast<f32x4*>(out_packed + (size_t)row * (H / 2));
    float qa0 = (float)((double)va.x * inv);
    float qa1 = (float)((double)va.y * inv);
    float qa2 = (float)((double)va.z * inv);
    float qa3 = (float)((double)va.w * inv);
    float qb0 = (float)((double)vb.x * inv);
    float qb1 = (float)((double)vb.y * inv);
    float qb2 = (float)((double)vb.z * inv);
    float qb3 = (float)((double)vb.w * inv);
    int a0 = (int)rintf(qa0); a0 = max(-8, min(7, a0));
    int a1 = (int)rintf(qa1); a1 = max(-8, min(7, a1));
    int a2 = (int)rintf(qa2); a2 = max(-8, min(7, a2));
    int a3 = (int)rintf(qa3); a3 = max(-8, min(7, a3));
    int b0 = (int)rintf(qb0); b0 = max(-8, min(7, b0));
    int b1 = (int)rintf(qb1); b1 = max(-8, min(7, b1));
    int b2 = (int)rintf(qb2); b2 = max(-8, min(7, b2));
    int b3 = (int)rintf(qb3); b3 = max(-8, min(7, b3));
    f32x4 o;
    o.x = (float)(signed char)((((a1 & 0xF) << 4) | (a0 & 0xF)) & 0xFF);
    o.y = (float)(signed char)((((a3 & 0xF) << 4) | (a2 & 0xF)) & 0xFF);
    o.z = (float)(signed char)((((b1 & 0xF) << 4) | (b0 & 0xF)) & 0xFF);
    o.w = (float)(signed char)((((b3 & 0xF) << 4) | (b2 & 0xF)) & 0xFF);
    __builtin_nontemporal_store(o, &outp[t]);

    if (t == 0) out_scales[row] = s;
}

extern "C" void kernel_launch(void* const* d_in, const int* in_sizes, int n_in,
                              void* d_out, int out_size, void* d_ws, size_t ws_size,
                              hipStream_t stream) {
    const float* x = (const float*)d_in[0];
    const int n = in_sizes[0];          // 4*2048*4096
    const int rows = n / H;             // 8192
    float* out = (float*)d_out;
    float* out_packed = out;            // n/2 packed values (as float)
    float* out_scales = out + (size_t)n / 2;  // rows scales

    const float r7 = 1.0f / 7.0f;       // compile-time fold: fl32(1/7)
    quant_int4_kernel<<<rows, BLOCK, 0, stream>>>(x, out_packed, out_scales, r7);
}